// Round 3
// baseline (410.943 us; speedup 1.0000x reference)
//
#include <hip/hip_runtime.h>
#include <hip/hip_bf16.h>
#include <math.h>

#define DIM 2048
#define NH 32
#define NKV 8
#define HD 64
#define SEQ 2048
#define BATCH 2
#define MTOT (BATCH*SEQ)          // 4096
#define QKV_N ((NH + 2*NKV)*HD)   // 3072
#define QSCALE 0.18033688011112042f   // log2(e)/8

typedef __bf16 bf16x8 __attribute__((ext_vector_type(8)));
typedef float f32x4 __attribute__((ext_vector_type(4)));

#if __has_builtin(__builtin_amdgcn_exp2f)
#define EXP2F __builtin_amdgcn_exp2f
#else
#define EXP2F exp2f
#endif

__device__ __forceinline__ void gld_lds16(const void* g, void* l) {
  __builtin_amdgcn_global_load_lds((__attribute__((address_space(1))) void*)g,
                                   (__attribute__((address_space(3))) void*)l,
                                   16, 0, 0);
}

// ---------------- elementwise: fp32 -> bf16 ----------------
__global__ void cvt_x_kernel(const float* __restrict__ src, __hip_bfloat16* __restrict__ dst, int n4) {
  int i = blockIdx.x * 256 + threadIdx.x;
  if (i >= n4) return;
  float4 v = ((const float4*)src)[i];
  union { __hip_bfloat16 h[4]; uint2 u; } t;
  t.h[0] = __float2bfloat16(v.x); t.h[1] = __float2bfloat16(v.y);
  t.h[2] = __float2bfloat16(v.z); t.h[3] = __float2bfloat16(v.w);
  ((uint2*)dst)[i] = t.u;
}

// ---------------- transpose + convert: src R x C fp32 -> dst C x R bf16 ----------------
__global__ void transpose_cvt_kernel(const float* __restrict__ src, __hip_bfloat16* __restrict__ dst,
                                     int R, int C) {
  __shared__ float tile[32][33];
  int c0 = blockIdx.x * 32, r0 = blockIdx.y * 32;
  int tx = threadIdx.x & 31, ty = threadIdx.x >> 5;
  #pragma unroll
  for (int i = ty; i < 32; i += 8)
    tile[i][tx] = src[(size_t)(r0 + i) * C + c0 + tx];
  __syncthreads();
  #pragma unroll
  for (int i = ty; i < 32; i += 8)
    dst[(size_t)(c0 + i) * R + r0 + tx] = __float2bfloat16(tile[tx][i]);
}

// ---------------- QKV GEMM (bf16 MFMA) with fused RoPE + head-major scatter ----------------
// A[M=4096][K=2048] * Bt[N=3072][K]^T. Epilogue: Q cols roped+scaled by log2e/8,
// K cols roped, V cols plain; written head-major.
__global__ __launch_bounds__(256) void gemm_qkv_rope_kernel(const __hip_bfloat16* __restrict__ A,
                                                            const __hip_bfloat16* __restrict__ Bt,
                                                            const float* __restrict__ freqs,
                                                            __hip_bfloat16* __restrict__ Qb,
                                                            __hip_bfloat16* __restrict__ Kb,
                                                            __hip_bfloat16* __restrict__ Vb) {
  __shared__ __hip_bfloat16 As[128 * 32];
  __shared__ __hip_bfloat16 Bs[128 * 32];
  const int tid = threadIdx.x;
  const int w = tid >> 6, lane = tid & 63, ln = lane & 15, quad = lane >> 4;
  const int m0 = blockIdx.y * 128, n0 = blockIdx.x * 128;
  const int wm = (w >> 1) * 64, wn = (w & 1) * 64;
  const int srow = w * 16 + (lane >> 2), scol = (lane & 3) * 8;
  const __hip_bfloat16* Ag = A + (size_t)(m0 + srow) * DIM + scol;
  const __hip_bfloat16* Bg = Bt + (size_t)(n0 + srow) * DIM + scol;
  __hip_bfloat16* AsW = &As[w * 512];
  __hip_bfloat16* BsW = &Bs[w * 512];
  f32x4 acc[4][4] = {};
  for (int k0 = 0; k0 < DIM; k0 += 32) {
    gld_lds16(Ag + k0, AsW);
    gld_lds16(Ag + 64 * (size_t)DIM + k0, AsW + 2048);
    gld_lds16(Bg + k0, BsW);
    gld_lds16(Bg + 64 * (size_t)DIM + k0, BsW + 2048);
    __syncthreads();
    bf16x8 af[4], bf[4];
    #pragma unroll
    for (int i = 0; i < 4; i++)
      af[i] = *(const bf16x8*)&As[(wm + i * 16 + ln) * 32 + quad * 8];
    #pragma unroll
    for (int j = 0; j < 4; j++)
      bf[j] = *(const bf16x8*)&Bs[(wn + j * 16 + ln) * 32 + quad * 8];
    #pragma unroll
    for (int i = 0; i < 4; i++)
      #pragma unroll
      for (int j = 0; j < 4; j++)
        acc[i][j] = __builtin_amdgcn_mfma_f32_16x16x32_bf16(af[i], bf[j], acc[i][j], 0, 0, 0);
    __syncthreads();
  }
  // epilogue: region is block-uniform (128-col tiles align with Q/K/V boundaries)
  const int region = (n0 >= 2560) ? 2 : (n0 >= 2048 ? 1 : 0);
  #pragma unroll
  for (int i = 0; i < 4; i++) {
    #pragma unroll
    for (int j = 0; j < 4; j++) {
      const int n = n0 + wn + j * 16 + ln;
      const int d = n & 63;
      #pragma unroll
      for (int r = 0; r < 4; r++) {
        const int m = m0 + wm + i * 16 + quad * 4 + r;
        const int bb = m >> 11, s = m & 2047;
        float v = acc[i][j][r];
        if (region == 2) {
          Vb[((size_t)(bb * NKV + ((n - 2560) >> 6)) * SEQ + s) * HD + d] = __float2bfloat16(v);
        } else {
          float p = __shfl_xor(v, 1);
          const float2 fc = *(const float2*)&freqs[s * 64 + (d & ~1)];
          float o = (d & 1) ? (v * fc.x + p * fc.y) : (v * fc.x - p * fc.y);
          if (region == 0)
            Qb[((size_t)(bb * NH + (n >> 6)) * SEQ + s) * HD + d] = __float2bfloat16(o * QSCALE);
          else
            Kb[((size_t)(bb * NKV + ((n - 2048) >> 6)) * SEQ + s) * HD + d] = __float2bfloat16(o);
        }
      }
    }
  }
}

// ---------------- generic bf16 GEMM (for WO), fp32 out ----------------
__global__ __launch_bounds__(256) void gemm_bt_f32_kernel(const __hip_bfloat16* __restrict__ A,
                                                          const __hip_bfloat16* __restrict__ Bt,
                                                          float* __restrict__ C, int M, int N, int K) {
  __shared__ __hip_bfloat16 As[128 * 32];
  __shared__ __hip_bfloat16 Bs[128 * 32];
  const int tid = threadIdx.x;
  const int w = tid >> 6, lane = tid & 63, ln = lane & 15, quad = lane >> 4;
  const int m0 = blockIdx.y * 128, n0 = blockIdx.x * 128;
  const int wm = (w >> 1) * 64, wn = (w & 1) * 64;
  const int srow = w * 16 + (lane >> 2), scol = (lane & 3) * 8;
  const __hip_bfloat16* Ag = A + (size_t)(m0 + srow) * K + scol;
  const __hip_bfloat16* Bg = Bt + (size_t)(n0 + srow) * K + scol;
  __hip_bfloat16* AsW = &As[w * 512];
  __hip_bfloat16* BsW = &Bs[w * 512];
  f32x4 acc[4][4] = {};
  for (int k0 = 0; k0 < K; k0 += 32) {
    gld_lds16(Ag + k0, AsW);
    gld_lds16(Ag + 64 * (size_t)K + k0, AsW + 2048);
    gld_lds16(Bg + k0, BsW);
    gld_lds16(Bg + 64 * (size_t)K + k0, BsW + 2048);
    __syncthreads();
    bf16x8 af[4], bf[4];
    #pragma unroll
    for (int i = 0; i < 4; i++)
      af[i] = *(const bf16x8*)&As[(wm + i * 16 + ln) * 32 + quad * 8];
    #pragma unroll
    for (int j = 0; j < 4; j++)
      bf[j] = *(const bf16x8*)&Bs[(wn + j * 16 + ln) * 32 + quad * 8];
    #pragma unroll
    for (int i = 0; i < 4; i++)
      #pragma unroll
      for (int j = 0; j < 4; j++)
        acc[i][j] = __builtin_amdgcn_mfma_f32_16x16x32_bf16(af[i], bf[j], acc[i][j], 0, 0, 0);
    __syncthreads();
  }
  #pragma unroll
  for (int i = 0; i < 4; i++) {
    const int r0 = m0 + wm + i * 16 + quad * 4;
    #pragma unroll
    for (int j = 0; j < 4; j++) {
      const int cc = n0 + wn + j * 16 + ln;
      #pragma unroll
      for (int r = 0; r < 4; r++)
        C[(size_t)(r0 + r) * N + cc] = acc[i][j][r];
    }
  }
}

// ---------------- flash-style causal GQA attention ----------------
// No-max softmax (Q pre-scaled by log2e/8; P = exp2(s) directly).
// grid (16, NH, B): block handles q-tile t = 15-bx (128 rows), big tiles dispatched first.
// 4 waves x 32 q-rows; KV tile 128 staged per barrier (K via swizzled global_load_lds,
// V via register prefetch + transposed scatter), processed as two 64-KV sub-rounds.
__global__ __launch_bounds__(256, 3) void attn_kernel(const __hip_bfloat16* __restrict__ Q,
                                                      const __hip_bfloat16* __restrict__ Kg,
                                                      const __hip_bfloat16* __restrict__ Vg,
                                                      __hip_bfloat16* __restrict__ O) {
  __shared__ __hip_bfloat16 Ks[128 * 64];     // chunk-swizzled: phys = kv*8 + (dBlk ^ (kv&7))
  __shared__ __hip_bfloat16 Vs[64 * 136];     // [d][s ^ ((d>>4&3)<<4)], stride 136
  __shared__ __hip_bfloat16 Ps[4][32 * 72];   // per-wave P, col ^ (quad<<4), stride 72
  const int t = 15 - (int)blockIdx.x;
  const int h = blockIdx.y, b = blockIdx.z;
  const int kvh = h >> 2;
  const int tid = threadIdx.x, w = tid >> 6, lane = tid & 63, ln = lane & 15, quad = lane >> 4;
  const size_t qbase = (size_t)(b * NH + h) * SEQ * HD;
  const size_t kbase = (size_t)(b * NKV + kvh) * SEQ * HD;

  // K gld lane mapping: phys chunk = c*256 + tid -> kv = phys>>3, dBlk = (phys&7)^(kv&7)
  const __hip_bfloat16* Kgl = Kg + kbase + (size_t)(tid >> 3) * 64 + (size_t)(((tid & 7) ^ ((tid >> 3) & 7)) * 8);
  // V scatter mapping (proven 2-way-free in round 2)
  const int vrow = tid >> 2, vcb = (tid & 3) * 16, vsw = (tid & 3) << 4;
  const int psw = ((ln >> 2) & 3) << 4;

  const int qgw = t * 128 + w * 32;
  bf16x8 qf[2][2];
  #pragma unroll
  for (int f = 0; f < 2; f++)
    #pragma unroll
    for (int kt = 0; kt < 2; kt++)
      qf[f][kt] = *(const bf16x8*)(Q + qbase + (size_t)(qgw + f * 16 + ln) * HD + kt * 32 + quad * 8);
  f32x4 Oacc[2][4] = {};
  float lrow[2][4] = {};
  union { unsigned short u[8]; bf16x8 v; } onesu;
  #pragma unroll
  for (int i = 0; i < 8; i++) onesu.u[i] = 0x3F80;
  const bf16x8 ones = onesu.v;

  // preload V tile 0
  uint4 vd[2][2];
  #pragma unroll
  for (int bt = 0; bt < 2; bt++)
    #pragma unroll
    for (int cc = 0; cc < 2; cc++)
      vd[bt][cc] = *(const uint4*)(Vg + kbase + (size_t)(bt * 64 + vrow) * HD + vcb + cc * 8);

  for (int j = 0; j <= t; j++) {
    // async K stage (16 KB, 4 calls)
    #pragma unroll
    for (int c = 0; c < 4; c++)
      gld_lds16(Kgl + (size_t)j * 8192 + c * 2048, &Ks[c * 2048 + w * 512]);
    // V scatter from regs
    #pragma unroll
    for (int bt = 0; bt < 2; bt++)
      #pragma unroll
      for (int cc = 0; cc < 2; cc++) {
        const __hip_bfloat16* vp = (const __hip_bfloat16*)&vd[bt][cc];
        const int col = vcb + cc * 8;
        const int sr = (bt * 64 + vrow) ^ vsw;
        #pragma unroll
        for (int e = 0; e < 8; e++)
          Vs[(col + e) * 136 + sr] = vp[e];
      }
    __syncthreads();
    // prefetch next V tile (in flight during compute)
    if (j < t) {
      #pragma unroll
      for (int bt = 0; bt < 2; bt++)
        #pragma unroll
        for (int cc = 0; cc < 2; cc++)
          vd[bt][cc] = *(const uint4*)(Vg + kbase + (size_t)((j + 1) * 128 + bt * 64 + vrow) * HD + vcb + cc * 8);
    }
    const bool lastIter = (j == t);
    #pragma unroll
    for (int s2 = 0; s2 < 2; s2++) {
      if (lastIter && s2 * 64 > w * 32 + 31) continue;   // wave entirely above diagonal
      bf16x8 kf[4][2];
      #pragma unroll
      for (int nt = 0; nt < 4; nt++)
        #pragma unroll
        for (int kt = 0; kt < 2; kt++) {
          const int kv = s2 * 64 + nt * 16 + ln;
          kf[nt][kt] = *(const bf16x8*)&Ks[(kv * 8 + ((kt * 4 + quad) ^ (ln & 7))) * 8];
        }
      #pragma unroll
      for (int f = 0; f < 2; f++) {
        if (lastIter && s2 * 64 > w * 32 + f * 16 + 15) continue;
        f32x4 sf[4];
        #pragma unroll
        for (int nt = 0; nt < 4; nt++) {
          f32x4 s = {};
          s = __builtin_amdgcn_mfma_f32_16x16x32_bf16(qf[f][0], kf[nt][0], s, 0, 0, 0);
          s = __builtin_amdgcn_mfma_f32_16x16x32_bf16(qf[f][1], kf[nt][1], s, 0, 0, 0);
          sf[nt] = s;
        }
        if (lastIter && s2 * 64 + 63 > w * 32 + f * 16) {
          const int qr = w * 32 + f * 16 + quad * 4;
          #pragma unroll
          for (int nt = 0; nt < 4; nt++) {
            const int kg = s2 * 64 + nt * 16 + ln;
            #pragma unroll
            for (int r = 0; r < 4; r++)
              if (kg > qr + r) sf[nt][r] = -1.0e38f;
          }
        }
        #pragma unroll
        for (int nt = 0; nt < 4; nt++)
          #pragma unroll
          for (int r = 0; r < 4; r++)
            Ps[w][(f * 16 + quad * 4 + r) * 72 + ((nt * 16 + ln) ^ (quad << 4))] =
                __float2bfloat16(EXP2F(sf[nt][r]));
      }
      #pragma unroll
      for (int f = 0; f < 2; f++) {
        if (lastIter && s2 * 64 > w * 32 + f * 16 + 15) continue;
        f32x4 ls = {};
        #pragma unroll
        for (int kt = 0; kt < 2; kt++) {
          bf16x8 pf = *(const bf16x8*)&Ps[w][(f * 16 + ln) * 72 + ((kt * 32 + quad * 8) ^ psw)];
          ls = __builtin_amdgcn_mfma_f32_16x16x32_bf16(pf, ones, ls, 0, 0, 0);
          #pragma unroll
          for (int dt = 0; dt < 4; dt++) {
            bf16x8 vf = *(const bf16x8*)&Vs[(dt * 16 + ln) * 136 + s2 * 64 + ((kt * 32 + quad * 8) ^ (dt << 4))];
            Oacc[f][dt] = __builtin_amdgcn_mfma_f32_16x16x32_bf16(pf, vf, Oacc[f][dt], 0, 0, 0);
          }
        }
        #pragma unroll
        for (int r = 0; r < 4; r++) lrow[f][r] += ls[r];
      }
      __syncthreads();
    }
  }
  // epilogue: out[b][s][h*64+d] = O/l
  #pragma unroll
  for (int f = 0; f < 2; f++) {
    const int so = qgw + f * 16 + quad * 4;
    #pragma unroll
    for (int r = 0; r < 4; r++) {
      const float inv = 1.0f / lrow[f][r];
      #pragma unroll
      for (int dt = 0; dt < 4; dt++)
        O[((size_t)(b * SEQ) + so + r) * DIM + h * HD + dt * 16 + ln] =
            __float2bfloat16(Oacc[f][dt][r] * inv);
    }
  }
}

extern "C" void kernel_launch(void* const* d_in, const int* in_sizes, int n_in,
                              void* d_out, int out_size, void* d_ws, size_t ws_size,
                              hipStream_t stream) {
  const float* x     = (const float*)d_in[0];
  const float* freqs = (const float*)d_in[1];
  const float* wqkv  = (const float*)d_in[2];
  const float* wo    = (const float*)d_in[3];
  float* out = (float*)d_out;

  char* ws = (char*)d_ws;
  __hip_bfloat16* xb    = (__hip_bfloat16*)ws; ws += (size_t)MTOT * DIM * 2;
  __hip_bfloat16* wqkvT = (__hip_bfloat16*)ws; ws += (size_t)QKV_N * DIM * 2;
  __hip_bfloat16* woT   = (__hip_bfloat16*)ws; ws += (size_t)DIM * DIM * 2;
  __hip_bfloat16* Qb    = (__hip_bfloat16*)ws; ws += (size_t)BATCH * NH * SEQ * HD * 2;
  __hip_bfloat16* Kb    = (__hip_bfloat16*)ws; ws += (size_t)BATCH * NKV * SEQ * HD * 2;
  __hip_bfloat16* Vb    = (__hip_bfloat16*)ws; ws += (size_t)BATCH * NKV * SEQ * HD * 2;
  __hip_bfloat16* attnb = (__hip_bfloat16*)ws; ws += (size_t)MTOT * DIM * 2;

  cvt_x_kernel<<<(MTOT * DIM / 4 + 255) / 256, 256, 0, stream>>>(x, xb, MTOT * DIM / 4);
  transpose_cvt_kernel<<<dim3(QKV_N / 32, DIM / 32), 256, 0, stream>>>(wqkv, wqkvT, DIM, QKV_N);
  transpose_cvt_kernel<<<dim3(DIM / 32, DIM / 32), 256, 0, stream>>>(wo, woT, DIM, DIM);
  gemm_qkv_rope_kernel<<<dim3(QKV_N / 128, MTOT / 128), 256, 0, stream>>>(
      xb, wqkvT, freqs, Qb, Kb, Vb);
  attn_kernel<<<dim3(16, NH, BATCH), 256, 0, stream>>>(Qb, Kb, Vb, attnb);
  gemm_bt_f32_kernel<<<dim3(DIM / 128, MTOT / 128), 256, 0, stream>>>(
      attnb, woT, out, MTOT, DIM, DIM);
}

// Round 4
// 364.656 us; speedup vs baseline: 1.1269x; 1.1269x over previous
//
#include <hip/hip_runtime.h>
#include <hip/hip_bf16.h>
#include <math.h>

#define DIM 2048
#define NH 32
#define NKV 8
#define HD 64
#define SEQ 2048
#define BATCH 2
#define MTOT (BATCH*SEQ)          // 4096
#define QKV_N ((NH + 2*NKV)*HD)   // 3072
#define QSCALE 0.18033688011112042f   // log2(e)/8

typedef __bf16 bf16x8 __attribute__((ext_vector_type(8)));
typedef float f32x4 __attribute__((ext_vector_type(4)));

#if __has_builtin(__builtin_amdgcn_exp2f)
#define EXP2F __builtin_amdgcn_exp2f
#else
#define EXP2F exp2f
#endif

__device__ __forceinline__ void gld_lds16(const void* g, void* l) {
  __builtin_amdgcn_global_load_lds((__attribute__((address_space(1))) void*)g,
                                   (__attribute__((address_space(3))) void*)l,
                                   16, 0, 0);
}

// ---------------- elementwise: fp32 -> bf16 ----------------
__global__ void cvt_x_kernel(const float* __restrict__ src, __hip_bfloat16* __restrict__ dst, int n4) {
  int i = blockIdx.x * 256 + threadIdx.x;
  if (i >= n4) return;
  float4 v = ((const float4*)src)[i];
  union { __hip_bfloat16 h[4]; uint2 u; } t;
  t.h[0] = __float2bfloat16(v.x); t.h[1] = __float2bfloat16(v.y);
  t.h[2] = __float2bfloat16(v.z); t.h[3] = __float2bfloat16(v.w);
  ((uint2*)dst)[i] = t.u;
}

// ---------------- transpose + convert: src R x C fp32 -> dst C x R bf16 ----------------
__global__ void transpose_cvt_kernel(const float* __restrict__ src, __hip_bfloat16* __restrict__ dst,
                                     int R, int C) {
  __shared__ float tile[32][33];
  int c0 = blockIdx.x * 32, r0 = blockIdx.y * 32;
  int tx = threadIdx.x & 31, ty = threadIdx.x >> 5;
  #pragma unroll
  for (int i = ty; i < 32; i += 8)
    tile[i][tx] = src[(size_t)(r0 + i) * C + c0 + tx];
  __syncthreads();
  #pragma unroll
  for (int i = ty; i < 32; i += 8)
    dst[(size_t)(c0 + i) * R + r0 + tx] = __float2bfloat16(tile[tx][i]);
}

// ---------------- QKV GEMM, 2-wave 64x128 tile, fused RoPE + head-major scatter ----------------
// grid 1536 (1-D, XCD-swizzled): by = (id&7)*8 + ((id>>3)&7) in [0,64), bx = id>>6 in [0,24)
__global__ __launch_bounds__(128) void gemm_qkv_rope_kernel(const __hip_bfloat16* __restrict__ A,
                                                            const __hip_bfloat16* __restrict__ Bt,
                                                            const float* __restrict__ freqs,
                                                            __hip_bfloat16* __restrict__ Qb,
                                                            __hip_bfloat16* __restrict__ Kb,
                                                            __hip_bfloat16* __restrict__ Vb) {
  __shared__ __hip_bfloat16 As[64 * 32];    // 4 KB
  __shared__ __hip_bfloat16 Bs[128 * 32];   // 8 KB
  const int tid = threadIdx.x;
  const int w = tid >> 6, lane = tid & 63, ln = lane & 15, quad = lane >> 4;
  const int id = blockIdx.x;
  const int by = (id & 7) * 8 + ((id >> 3) & 7);
  const int bx = id >> 6;
  const int m0 = by * 64, n0 = bx * 128;
  const int K = DIM;
  const __hip_bfloat16* Ag = A + (size_t)(m0 + w * 32 + (lane >> 2)) * K + (lane & 3) * 8;
  const __hip_bfloat16* Bg = Bt + (size_t)(n0 + w * 64 + (lane >> 2)) * K + (lane & 3) * 8;
  __hip_bfloat16* AsW = &As[w * 1024];
  __hip_bfloat16* BsW = &Bs[w * 2048];
  f32x4 acc[4][4] = {};
  for (int k0 = 0; k0 < K; k0 += 32) {
    gld_lds16(Ag + k0, AsW);
    gld_lds16(Ag + (size_t)16 * K + k0, AsW + 512);
    #pragma unroll
    for (int c = 0; c < 4; c++)
      gld_lds16(Bg + (size_t)(c * 16) * K + k0, BsW + c * 512);
    __syncthreads();
    bf16x8 af[4], bf[4];
    #pragma unroll
    for (int i = 0; i < 4; i++)
      af[i] = *(const bf16x8*)&As[(i * 16 + ln) * 32 + quad * 8];
    #pragma unroll
    for (int j = 0; j < 4; j++)
      bf[j] = *(const bf16x8*)&Bs[(w * 64 + j * 16 + ln) * 32 + quad * 8];
    #pragma unroll
    for (int i = 0; i < 4; i++)
      #pragma unroll
      for (int j = 0; j < 4; j++)
        acc[i][j] = __builtin_amdgcn_mfma_f32_16x16x32_bf16(af[i], bf[j], acc[i][j], 0, 0, 0);
    __syncthreads();
  }
  // epilogue: rope + head-major scatter. region is block-uniform (n0 multiple of 128)
  const int region = (n0 >= 2560) ? 2 : (n0 >= 2048 ? 1 : 0);
  #pragma unroll
  for (int i = 0; i < 4; i++) {
    #pragma unroll
    for (int j = 0; j < 4; j++) {
      const int n = n0 + w * 64 + j * 16 + ln;
      const int d = n & 63;
      #pragma unroll
      for (int r = 0; r < 4; r++) {
        const int m = m0 + i * 16 + quad * 4 + r;
        const int bb = m >> 11, s = m & 2047;
        float v = acc[i][j][r];
        if (region == 2) {
          Vb[((size_t)(bb * NKV + ((n - 2560) >> 6)) * SEQ + s) * HD + d] = __float2bfloat16(v);
        } else {
          float p = __shfl_xor(v, 1);
          const float2 fc = *(const float2*)&freqs[s * 64 + (d & ~1)];
          float o = (d & 1) ? (v * fc.x + p * fc.y) : (v * fc.x - p * fc.y);
          if (region == 0)
            Qb[((size_t)(bb * NH + (n >> 6)) * SEQ + s) * HD + d] = __float2bfloat16(o * QSCALE);
          else
            Kb[((size_t)(bb * NKV + ((n - 2048) >> 6)) * SEQ + s) * HD + d] = __float2bfloat16(o);
        }
      }
    }
  }
}

// ---------------- WO GEMM, 2-wave 64x128 tile, fp32 out ----------------
// grid 1024: by = (id&7)*8 + ((id>>3)&7) in [0,64), bx = id>>6 in [0,16)
__global__ __launch_bounds__(128) void gemm_wo_kernel(const __hip_bfloat16* __restrict__ A,
                                                      const __hip_bfloat16* __restrict__ Bt,
                                                      float* __restrict__ C) {
  __shared__ __hip_bfloat16 As[64 * 32];
  __shared__ __hip_bfloat16 Bs[128 * 32];
  const int tid = threadIdx.x;
  const int w = tid >> 6, lane = tid & 63, ln = lane & 15, quad = lane >> 4;
  const int id = blockIdx.x;
  const int by = (id & 7) * 8 + ((id >> 3) & 7);
  const int bx = id >> 6;
  const int m0 = by * 64, n0 = bx * 128;
  const int K = DIM, N = DIM;
  const __hip_bfloat16* Ag = A + (size_t)(m0 + w * 32 + (lane >> 2)) * K + (lane & 3) * 8;
  const __hip_bfloat16* Bg = Bt + (size_t)(n0 + w * 64 + (lane >> 2)) * K + (lane & 3) * 8;
  __hip_bfloat16* AsW = &As[w * 1024];
  __hip_bfloat16* BsW = &Bs[w * 2048];
  f32x4 acc[4][4] = {};
  for (int k0 = 0; k0 < K; k0 += 32) {
    gld_lds16(Ag + k0, AsW);
    gld_lds16(Ag + (size_t)16 * K + k0, AsW + 512);
    #pragma unroll
    for (int c = 0; c < 4; c++)
      gld_lds16(Bg + (size_t)(c * 16) * K + k0, BsW + c * 512);
    __syncthreads();
    bf16x8 af[4], bf[4];
    #pragma unroll
    for (int i = 0; i < 4; i++)
      af[i] = *(const bf16x8*)&As[(i * 16 + ln) * 32 + quad * 8];
    #pragma unroll
    for (int j = 0; j < 4; j++)
      bf[j] = *(const bf16x8*)&Bs[(w * 64 + j * 16 + ln) * 32 + quad * 8];
    #pragma unroll
    for (int i = 0; i < 4; i++)
      #pragma unroll
      for (int j = 0; j < 4; j++)
        acc[i][j] = __builtin_amdgcn_mfma_f32_16x16x32_bf16(af[i], bf[j], acc[i][j], 0, 0, 0);
    __syncthreads();
  }
  #pragma unroll
  for (int i = 0; i < 4; i++) {
    const int r0 = m0 + i * 16 + quad * 4;
    #pragma unroll
    for (int j = 0; j < 4; j++) {
      const int cc = n0 + w * 64 + j * 16 + ln;
      #pragma unroll
      for (int r = 0; r < 4; r++)
        C[(size_t)(r0 + r) * N + cc] = acc[i][j][r];
    }
  }
}

// ---------------- flash-style causal GQA attention ----------------
// No-max softmax (Q pre-scaled by log2e/8; P = exp2(s)).
// grid 1024 (1-D, XCD-swizzled): xcd = id&7 owns (b,kvh) combos {2*xcd, 2*xcd+1};
// within combo: t = 15-(slot>>2) (LPT), head group g = slot&3.
// 4 waves x 32 q-rows (128-row q-tile); KV tile 128 per barrier-pair, two 64-KV sub-rounds.
__global__ __launch_bounds__(256, 3) void attn_kernel(const __hip_bfloat16* __restrict__ Q,
                                                      const __hip_bfloat16* __restrict__ Kg,
                                                      const __hip_bfloat16* __restrict__ Vg,
                                                      __hip_bfloat16* __restrict__ O) {
  __shared__ __hip_bfloat16 Ks[128 * 64];     // chunk-swizzled: phys = kv*8 + (dBlk ^ (kv&7))
  __shared__ __hip_bfloat16 Vs[64 * 136];     // [d][s ^ ((d>>4&3)<<4)], stride 136
  __shared__ __hip_bfloat16 Ps[4][32 * 72];   // per-wave P, col ^ (quad<<4), stride 72
  const int id = blockIdx.x;
  const int xcd = id & 7, slot = id >> 3;
  const int cmb = xcd * 2 + (slot >> 6);      // 0..15
  const int b = cmb >> 3, kvh = cmb & 7;
  const int s_ = slot & 63;
  const int t = 15 - (s_ >> 2);               // big tiles first per XCD
  const int h = kvh * 4 + (s_ & 3);
  const int tid = threadIdx.x, w = tid >> 6, lane = tid & 63, ln = lane & 15, quad = lane >> 4;
  const size_t qbase = (size_t)(b * NH + h) * SEQ * HD;
  const size_t kbase = (size_t)(b * NKV + kvh) * SEQ * HD;

  // K gld lane mapping: phys chunk = c*256 + tid -> kv = phys>>3, dBlk = (phys&7)^(kv&7)
  const __hip_bfloat16* Kgl = Kg + kbase + (size_t)(tid >> 3) * 64 + (size_t)(((tid & 7) ^ ((tid >> 3) & 7)) * 8);
  // V scatter mapping (2-way free)
  const int vrow = tid >> 2, vcb = (tid & 3) * 16, vsw = (tid & 3) << 4;
  const int psw = ((ln >> 2) & 3) << 4;

  const int qgw = t * 128 + w * 32;
  bf16x8 qf[2][2];
  #pragma unroll
  for (int f = 0; f < 2; f++)
    #pragma unroll
    for (int kt = 0; kt < 2; kt++)
      qf[f][kt] = *(const bf16x8*)(Q + qbase + (size_t)(qgw + f * 16 + ln) * HD + kt * 32 + quad * 8);
  f32x4 Oacc[2][4] = {};
  float lrow[2][4] = {};
  union { unsigned short u[8]; bf16x8 v; } onesu;
  #pragma unroll
  for (int i = 0; i < 8; i++) onesu.u[i] = 0x3F80;
  const bf16x8 ones = onesu.v;

  // preload V tile 0
  uint4 vd[2][2];
  #pragma unroll
  for (int bt = 0; bt < 2; bt++)
    #pragma unroll
    for (int cc = 0; cc < 2; cc++)
      vd[bt][cc] = *(const uint4*)(Vg + kbase + (size_t)(bt * 64 + vrow) * HD + vcb + cc * 8);

  for (int j = 0; j <= t; j++) {
    // async K stage (16 KB, 4 calls) + V scatter from regs
    #pragma unroll
    for (int c = 0; c < 4; c++)
      gld_lds16(Kgl + (size_t)j * 8192 + c * 2048, &Ks[c * 2048 + w * 512]);
    #pragma unroll
    for (int bt = 0; bt < 2; bt++)
      #pragma unroll
      for (int cc = 0; cc < 2; cc++) {
        const __hip_bfloat16* vp = (const __hip_bfloat16*)&vd[bt][cc];
        const int col = vcb + cc * 8;
        const int sr = (bt * 64 + vrow) ^ vsw;
        #pragma unroll
        for (int e = 0; e < 8; e++)
          Vs[(col + e) * 136 + sr] = vp[e];
      }
    __syncthreads();
    // prefetch next V tile (stays in flight through compute)
    if (j < t) {
      #pragma unroll
      for (int bt = 0; bt < 2; bt++)
        #pragma unroll
        for (int cc = 0; cc < 2; cc++)
          vd[bt][cc] = *(const uint4*)(Vg + kbase + (size_t)((j + 1) * 128 + bt * 64 + vrow) * HD + vcb + cc * 8);
    }
    const bool lastIter = (j == t);
    #pragma unroll
    for (int s2 = 0; s2 < 2; s2++) {
      if (lastIter && s2 * 64 > w * 32 + 31) continue;   // wave entirely above diagonal
      bf16x8 kf[4][2];
      #pragma unroll
      for (int nt = 0; nt < 4; nt++)
        #pragma unroll
        for (int kt = 0; kt < 2; kt++) {
          const int kv = s2 * 64 + nt * 16 + ln;
          kf[nt][kt] = *(const bf16x8*)&Ks[(kv * 8 + ((kt * 4 + quad) ^ (ln & 7))) * 8];
        }
      #pragma unroll
      for (int f = 0; f < 2; f++) {
        if (lastIter && s2 * 64 > w * 32 + f * 16 + 15) continue;
        f32x4 sf[4];
        #pragma unroll
        for (int nt = 0; nt < 4; nt++) {
          f32x4 s = {};
          s = __builtin_amdgcn_mfma_f32_16x16x32_bf16(qf[f][0], kf[nt][0], s, 0, 0, 0);
          s = __builtin_amdgcn_mfma_f32_16x16x32_bf16(qf[f][1], kf[nt][1], s, 0, 0, 0);
          sf[nt] = s;
        }
        if (lastIter && s2 * 64 + 63 > w * 32 + f * 16) {
          const int qr = w * 32 + f * 16 + quad * 4;
          #pragma unroll
          for (int nt = 0; nt < 4; nt++) {
            const int kg = s2 * 64 + nt * 16 + ln;
            #pragma unroll
            for (int r = 0; r < 4; r++)
              if (kg > qr + r) sf[nt][r] = -1.0e38f;
          }
        }
        #pragma unroll
        for (int nt = 0; nt < 4; nt++)
          #pragma unroll
          for (int r = 0; r < 4; r++)
            Ps[w][(f * 16 + quad * 4 + r) * 72 + ((nt * 16 + ln) ^ (quad << 4))] =
                __float2bfloat16(EXP2F(sf[nt][r]));
      }
      #pragma unroll
      for (int f = 0; f < 2; f++) {
        if (lastIter && s2 * 64 > w * 32 + f * 16 + 15) continue;
        f32x4 ls = {};
        #pragma unroll
        for (int kt = 0; kt < 2; kt++) {
          bf16x8 pf = *(const bf16x8*)&Ps[w][(f * 16 + ln) * 72 + ((kt * 32 + quad * 8) ^ psw)];
          ls = __builtin_amdgcn_mfma_f32_16x16x32_bf16(pf, ones, ls, 0, 0, 0);
          #pragma unroll
          for (int dt = 0; dt < 4; dt++) {
            bf16x8 vf = *(const bf16x8*)&Vs[(dt * 16 + ln) * 136 + s2 * 64 + ((kt * 32 + quad * 8) ^ (dt << 4))];
            Oacc[f][dt] = __builtin_amdgcn_mfma_f32_16x16x32_bf16(pf, vf, Oacc[f][dt], 0, 0, 0);
          }
        }
        #pragma unroll
        for (int r = 0; r < 4; r++) lrow[f][r] += ls[r];
      }
    }
    __syncthreads();   // protects Ks/Vs before next staging; all waves reach it
  }
  // epilogue: out[b][s][h*64+d] = O/l
  #pragma unroll
  for (int f = 0; f < 2; f++) {
    const int so = qgw + f * 16 + quad * 4;
    #pragma unroll
    for (int r = 0; r < 4; r++) {
      const float inv = 1.0f / lrow[f][r];
      #pragma unroll
      for (int dt = 0; dt < 4; dt++)
        O[((size_t)(b * SEQ) + so + r) * DIM + h * HD + dt * 16 + ln] =
            __float2bfloat16(Oacc[f][dt][r] * inv);
    }
  }
}

extern "C" void kernel_launch(void* const* d_in, const int* in_sizes, int n_in,
                              void* d_out, int out_size, void* d_ws, size_t ws_size,
                              hipStream_t stream) {
  const float* x     = (const float*)d_in[0];
  const float* freqs = (const float*)d_in[1];
  const float* wqkv  = (const float*)d_in[2];
  const float* wo    = (const float*)d_in[3];
  float* out = (float*)d_out;

  char* ws = (char*)d_ws;
  __hip_bfloat16* xb    = (__hip_bfloat16*)ws; ws += (size_t)MTOT * DIM * 2;
  __hip_bfloat16* wqkvT = (__hip_bfloat16*)ws; ws += (size_t)QKV_N * DIM * 2;
  __hip_bfloat16* woT   = (__hip_bfloat16*)ws; ws += (size_t)DIM * DIM * 2;
  __hip_bfloat16* Qb    = (__hip_bfloat16*)ws; ws += (size_t)BATCH * NH * SEQ * HD * 2;
  __hip_bfloat16* Kb    = (__hip_bfloat16*)ws; ws += (size_t)BATCH * NKV * SEQ * HD * 2;
  __hip_bfloat16* Vb    = (__hip_bfloat16*)ws; ws += (size_t)BATCH * NKV * SEQ * HD * 2;
  __hip_bfloat16* attnb = (__hip_bfloat16*)ws; ws += (size_t)MTOT * DIM * 2;

  cvt_x_kernel<<<(MTOT * DIM / 4 + 255) / 256, 256, 0, stream>>>(x, xb, MTOT * DIM / 4);
  transpose_cvt_kernel<<<dim3(QKV_N / 32, DIM / 32), 256, 0, stream>>>(wqkv, wqkvT, DIM, QKV_N);
  transpose_cvt_kernel<<<dim3(DIM / 32, DIM / 32), 256, 0, stream>>>(wo, woT, DIM, DIM);
  gemm_qkv_rope_kernel<<<1536, 128, 0, stream>>>(xb, wqkvT, freqs, Qb, Kb, Vb);
  attn_kernel<<<1024, 256, 0, stream>>>(Qb, Kb, Vb, attnb);
  gemm_wo_kernel<<<1024, 128, 0, stream>>>(attnb, woT, out);
}